// Round 4
// baseline (2046.634 us; speedup 1.0000x reference)
//
#include <hip/hip_runtime.h>
#include <cstdint>
#include <cstddef>

#define BATCH   65536
#define RANK_K  32769   // sorted_desc[32768] == 32769-th largest (1-indexed)

// ============ big GEMM (layers 1&2): C = relu((A*rowmask) @ B + bias), + per-row sum-of-squares partials ============
// v5: BM=256, BN=256, BK=16, 256 threads, 16x16 per thread, 1 wave/SIMD.
//   Rationale: at 16x8 the per-CU LDS unit (6 b128/kk/wave x 8 waves = 576 cyc)
//   outruns FMA issue (512 cyc) -> LDS-bound.  16x16 halves LDS bytes/FMA
//   (8 b128 per 256 FMA): 4 waves x 8 x 12 = 384 < 512 -> FMA-issue-bound.
//   acc[16][16]=256 regs lives in AGPRs (unified file; VALU reads/writes AGPRs
//   directly on CDNA) -> __launch_bounds__(256,1), 1 block/CU.
//   Register prefetch of tile t+1 between the barriers (mandatory at 1 block/CU:
//   no co-resident block covers global latency).  Bs granule-XOR swizzle
//   g' = g ^ ((g>>3)&7) (bijective per 64-granule row; 2-way access = free).
// BIT-EXACTNESS vs validated kernel: per-element k-chain identical (ascending,
// single-register fmaf chain), bias->relu->square identical.  Norm partials
// reproduce the OLD grouping exactly: thread's 16 cols = old 8-col groups
// {2tc,2tc+1}; block's 256 cols = old y-partials {2Y,2Y+1}; two-pass red[][17]
// reduction sums x=0..15 ascending exactly as before -> same partial values in
// the same normPart slots -> masks cannot flip.
template<bool MASKED>
__global__ __launch_bounds__(256, 1)
void gemm_relu_norm(const float* __restrict__ A, const float* __restrict__ B,
                    const float* __restrict__ bias, const float* __restrict__ mask,
                    float* __restrict__ C, float* __restrict__ normPart,
                    const int N, const int K)
{
    __shared__ float As[16][260];   // [k][row], +4 pad; row base 65 granules
    __shared__ float Bs[16][256];   // [k][col], granule-swizzled
    __shared__ float red[256][17];  // row-norm partial reduction (two passes)

    const int t    = threadIdx.x;
    const int tr   = t >> 4;          // 0..15 row group (16 rows each)
    const int tc   = t & 15;          // 0..15 col group (16 cols each)
    const int row0 = blockIdx.x * 256;
    const int col0 = blockIdx.y * 256;

    // A-load: thread t loads row (row0+t), 16 consecutive k per tile
    const float* Aptr = A + (size_t)(row0 + t) * K;
    // B-load: 16 k-rows x 256 cols; thread: k=t>>4, cols tc*16..+15
    const int bk = t >> 4;
    const float* Bptr = B + (size_t)bk * N + col0 + tc * 16;

    // swizzled Bs granule float-offsets (same for store and read -> data correct)
    const int g0 = ((tc << 2) + 0) ^ (tc >> 1);
    const int g1 = ((tc << 2) + 1) ^ (tc >> 1);
    const int g2 = ((tc << 2) + 2) ^ (tc >> 1);
    const int g3 = ((tc << 2) + 3) ^ (tc >> 1);
    const int bg0 = g0 << 2, bg1 = g1 << 2, bg2 = g2 << 2, bg3 = g3 << 2;

    float scale = 1.0f;
    if (MASKED) scale = mask[row0 + t];

    float acc[16][16];
    #pragma unroll
    for (int i = 0; i < 16; ++i)
        #pragma unroll
        for (int j = 0; j < 16; ++j) acc[i][j] = 0.0f;

    // ---- prologue: load tile 0 into registers ----
    float4 a0 = *(const float4*)(Aptr + 0);
    float4 a1 = *(const float4*)(Aptr + 4);
    float4 a2 = *(const float4*)(Aptr + 8);
    float4 a3 = *(const float4*)(Aptr + 12);
    float4 b0 = *(const float4*)(Bptr + 0);
    float4 b1 = *(const float4*)(Bptr + 4);
    float4 b2 = *(const float4*)(Bptr + 8);
    float4 b3 = *(const float4*)(Bptr + 12);

    for (int k0 = 0; k0 < K; k0 += 16) {
        // ---- stage current tile (regs -> LDS); scale applied here, matches ref ----
        if (MASKED) {
            a0.x *= scale; a0.y *= scale; a0.z *= scale; a0.w *= scale;
            a1.x *= scale; a1.y *= scale; a1.z *= scale; a1.w *= scale;
            a2.x *= scale; a2.y *= scale; a2.z *= scale; a2.w *= scale;
            a3.x *= scale; a3.y *= scale; a3.z *= scale; a3.w *= scale;
        }
        As[ 0][t] = a0.x; As[ 1][t] = a0.y; As[ 2][t] = a0.z; As[ 3][t] = a0.w;
        As[ 4][t] = a1.x; As[ 5][t] = a1.y; As[ 6][t] = a1.z; As[ 7][t] = a1.w;
        As[ 8][t] = a2.x; As[ 9][t] = a2.y; As[10][t] = a2.z; As[11][t] = a2.w;
        As[12][t] = a3.x; As[13][t] = a3.y; As[14][t] = a3.z; As[15][t] = a3.w;
        *(float4*)&Bs[bk][bg0] = b0;   // swizzled granule stores
        *(float4*)&Bs[bk][bg1] = b1;
        *(float4*)&Bs[bk][bg2] = b2;
        *(float4*)&Bs[bk][bg3] = b3;
        __syncthreads();

        // ---- issue next-tile loads NOW (drain at the NEXT barrier, ~8k cyc away) ----
        const int k0n = (k0 + 16 < K) ? (k0 + 16) : k0;   // clamp: last iter re-reads, never stored
        a0 = *(const float4*)(Aptr + k0n);
        a1 = *(const float4*)(Aptr + k0n + 4);
        a2 = *(const float4*)(Aptr + k0n + 8);
        a3 = *(const float4*)(Aptr + k0n + 12);
        b0 = *(const float4*)(Bptr + (size_t)k0n * N);
        b1 = *(const float4*)(Bptr + (size_t)k0n * N + 4);
        b2 = *(const float4*)(Bptr + (size_t)k0n * N + 8);
        b3 = *(const float4*)(Bptr + (size_t)k0n * N + 12);

        // ---- compute current tile from LDS ----
        #pragma unroll 8
        for (int kk = 0; kk < 16; ++kk) {
            float a_[16], b_[16];
            *(float4*)&a_[0]  = *(const float4*)&As[kk][tr*16];
            *(float4*)&a_[4]  = *(const float4*)&As[kk][tr*16 + 4];
            *(float4*)&a_[8]  = *(const float4*)&As[kk][tr*16 + 8];
            *(float4*)&a_[12] = *(const float4*)&As[kk][tr*16 + 12];
            *(float4*)&b_[0]  = *(const float4*)&Bs[kk][bg0];
            *(float4*)&b_[4]  = *(const float4*)&Bs[kk][bg1];
            *(float4*)&b_[8]  = *(const float4*)&Bs[kk][bg2];
            *(float4*)&b_[12] = *(const float4*)&Bs[kk][bg3];
            #pragma unroll
            for (int i = 0; i < 16; ++i)
                #pragma unroll
                for (int j = 0; j < 16; ++j)
                    acc[i][j] = fmaf(a_[i], b_[j], acc[i][j]);
        }
        __syncthreads();
    }

    float bv[16];
    #pragma unroll
    for (int j = 0; j < 16; ++j) bv[j] = bias[col0 + tc*16 + j];

    // bias -> relu in place (same per-element op and order as before)
    #pragma unroll
    for (int i = 0; i < 16; ++i)
        #pragma unroll
        for (int j = 0; j < 16; ++j)
            acc[i][j] = fmaxf(acc[i][j] + bv[j], 0.0f);

    #pragma unroll
    for (int i = 0; i < 16; ++i) {
        const size_t row = (size_t)(row0 + tr*16 + i);
        *(float4*)&C[row * N + col0 + tc*16]      = *(float4*)&acc[i][0];
        *(float4*)&C[row * N + col0 + tc*16 + 4]  = *(float4*)&acc[i][4];
        *(float4*)&C[row * N + col0 + tc*16 + 8]  = *(float4*)&acc[i][8];
        *(float4*)&C[row * N + col0 + tc*16 + 12] = *(float4*)&acc[i][12];
    }

    // per-row group sums: cols j=0..7 = old group 2tc, j=8..15 = old group 2tc+1
    // (fresh fmaf chains, j ascending — identical to old per-group chains)
    float slo[16], shi[16];
    #pragma unroll
    for (int i = 0; i < 16; ++i) {
        float s = 0.0f;
        #pragma unroll
        for (int j = 0; j < 8; ++j) s = fmaf(acc[i][j], acc[i][j], s);
        slo[i] = s;
        s = 0.0f;
        #pragma unroll
        for (int j = 8; j < 16; ++j) s = fmaf(acc[i][j], acc[i][j], s);
        shi[i] = s;
    }

    // pass 1: old y-partial p = 2*blockIdx.y (cols [col0, col0+128) -> threads tc<8)
    if (tc < 8) {
        #pragma unroll
        for (int i = 0; i < 16; ++i) {
            red[tr*16 + i][2*tc]     = slo[i];
            red[tr*16 + i][2*tc + 1] = shi[i];
        }
    }
    __syncthreads();
    {
        float s = 0.0f;
        #pragma unroll
        for (int x = 0; x < 16; ++x) s += red[t][x];    // fixed ascending order
        normPart[(size_t)(2*blockIdx.y) * BATCH + row0 + t] = s;
    }
    __syncthreads();
    // pass 2: old y-partial p = 2*blockIdx.y + 1 (cols [col0+128, col0+256))
    if (tc >= 8) {
        #pragma unroll
        for (int i = 0; i < 16; ++i) {
            red[tr*16 + i][2*(tc-8)]     = slo[i];
            red[tr*16 + i][2*(tc-8) + 1] = shi[i];
        }
    }
    __syncthreads();
    {
        float s = 0.0f;
        #pragma unroll
        for (int x = 0; x < 16; ++x) s += red[t][x];    // fixed ascending order
        normPart[(size_t)(2*blockIdx.y + 1) * BATCH + row0 + t] = s;
    }
}

// ============ deterministic partial-sum -> norm (sqrt in double = correctly-rounded fp32 sqrt) ============
__global__ __launch_bounds__(256)
void reduce_norms_kernel(const float* __restrict__ part, float* __restrict__ norms, const int nPart)
{
    const int i = blockIdx.x * 256 + threadIdx.x;
    float s = 0.0f;
    for (int p = 0; p < nPart; ++p) s += part[(size_t)p * BATCH + i];
    norms[i] = (float)sqrt((double)s);
}

// ============ exact 32769-th-largest via binary search on uint key space (no atomics) ============
__global__ __launch_bounds__(1024)
void select_kernel(const float* __restrict__ norms, float* __restrict__ maskOut,
                   float* __restrict__ thrOut)
{
    __shared__ int wsum[16];

    const int t = threadIdx.x;
    unsigned key[64];
    const float4* n4 = (const float4*)norms;
    #pragma unroll
    for (int i = 0; i < 16; ++i) {
        float4 v = n4[i * 1024 + t];
        key[i*4+0] = __float_as_uint(v.x);
        key[i*4+1] = __float_as_uint(v.y);
        key[i*4+2] = __float_as_uint(v.z);
        key[i*4+3] = __float_as_uint(v.w);      // nonneg floats -> monotone uint order
    }

    // V = min{ T : count(key > T) < RANK_K }  == exact RANK_K-th largest value
    unsigned lo = 0u, hi = 0x7F800000u;
    while (lo < hi) {                            // uniform across all threads
        const unsigned mid = lo + ((hi - lo) >> 1);
        int c = 0;
        #pragma unroll
        for (int i = 0; i < 64; ++i) c += (key[i] > mid) ? 1 : 0;
        #pragma unroll
        for (int off = 32; off > 0; off >>= 1) c += __shfl_down(c, off, 64);
        if ((t & 63) == 0) wsum[t >> 6] = c;
        __syncthreads();
        int total = 0;
        #pragma unroll
        for (int w = 0; w < 16; ++w) total += wsum[w];
        if (total < RANK_K) hi = mid; else lo = mid + 1;
        __syncthreads();
    }

    if (t == 0) thrOut[0] = __uint_as_float(lo);
    float4* m4 = (float4*)maskOut;
    #pragma unroll
    for (int i = 0; i < 16; ++i) {
        float4 m;
        m.x = (key[i*4+0] > lo) ? 1.0f : 0.0f;
        m.y = (key[i*4+1] > lo) ? 1.0f : 0.0f;
        m.z = (key[i*4+2] > lo) ? 1.0f : 0.0f;
        m.w = (key[i*4+3] > lo) ? 1.0f : 0.0f;   // strict > like reference
        m4[i * 1024 + t] = m;
    }
}

// ============ layer 3: h3 = relu((h2*m2) @ W3[256x10] + b3), full row norms ============
__global__ __launch_bounds__(256)
void layer3_kernel(const float* __restrict__ h2, const float* __restrict__ W3,
                   const float* __restrict__ b3, const float* __restrict__ mask2,
                   float* __restrict__ h3, float* __restrict__ norms3)
{
    __shared__ float wT[10][260];   // transposed W3 for b128 broadcast reads
    __shared__ float red[64][5];

    const int t    = threadIdx.x;
    const int r    = t & 63;
    const int g    = t >> 6;          // 0..3 column groups (3,3,3,1)
    const int j0   = g * 3;
    const int nj   = (g == 3) ? 1 : 3;
    const int row0 = blockIdx.x * 64;
    const int row  = row0 + r;

    for (int e = t; e < 2560; e += 256) wT[e % 10][e / 10] = W3[e];
    __syncthreads();

    const float m = mask2[row];
    const float* hrow = h2 + (size_t)row * 256;

    float acc[3] = {0.0f, 0.0f, 0.0f};
    for (int k = 0; k < 256; k += 4) {
        float4 v = *(const float4*)(hrow + k);
        v.x *= m; v.y *= m; v.z *= m; v.w *= m;
        float4 w0 = *(const float4*)&wT[j0][k];
        acc[0] += v.x*w0.x + v.y*w0.y + v.z*w0.z + v.w*w0.w;
        if (nj > 1) {
            float4 w1 = *(const float4*)&wT[j0+1][k];
            acc[1] += v.x*w1.x + v.y*w1.y + v.z*w1.z + v.w*w1.w;
            float4 w2 = *(const float4*)&wT[j0+2][k];
            acc[2] += v.x*w2.x + v.y*w2.y + v.z*w2.z + v.w*w2.w;
        }
    }

    float ss = 0.0f;
    for (int jj = 0; jj < nj; ++jj) {
        float v = fmaxf(acc[jj] + b3[j0 + jj], 0.0f);
        h3[(size_t)row * 10 + j0 + jj] = v;
        ss += v * v;
    }
    red[r][g] = ss;
    __syncthreads();
    if (t < 64) {
        float s = red[t][0] + red[t][1] + red[t][2] + red[t][3];  // fixed order
        norms3[row0 + t] = (float)sqrt((double)s);
    }
}

// ============ layer 4: h4 = (h3*m3) @ W4[10x10] + b4 (no relu), norms ============
__global__ __launch_bounds__(256)
void layer4_kernel(const float* __restrict__ h3, const float* __restrict__ W4,
                   const float* __restrict__ b4, const float* __restrict__ mask3,
                   float* __restrict__ h4, float* __restrict__ norms4)
{
    __shared__ float w[100];
    __shared__ float bb[10];
    const int t = threadIdx.x;
    if (t < 100) w[t] = W4[t];
    if (t < 10)  bb[t] = b4[t];
    __syncthreads();

    const int row = blockIdx.x * 256 + t;
    const float m = mask3[row];
    const float* hr = h3 + (size_t)row * 10;
    float v[10];
    #pragma unroll
    for (int k = 0; k < 10; ++k) v[k] = hr[k] * m;

    float s = 0.0f;
    #pragma unroll
    for (int j = 0; j < 10; ++j) {
        float a = 0.0f;
        #pragma unroll
        for (int k = 0; k < 10; ++k) a = fmaf(v[k], w[k*10 + j], a);
        a += bb[j];                     // dot then +bias (matches ref)
        h4[(size_t)row * 10 + j] = a;
        s = fmaf(a, a, s);
    }
    norms4[row] = (float)sqrt((double)s);
}

// ============ final: out = softmax(h4 * m4) ============
__global__ __launch_bounds__(256)
void softmax_kernel(const float* __restrict__ h4, const float* __restrict__ mask4,
                    float* __restrict__ out)
{
    const int t   = threadIdx.x;
    const int row = blockIdx.x * 256 + t;
    const float m = mask4[row];
    const float* hr = h4 + (size_t)row * 10;
    float v[10];
    #pragma unroll
    for (int k = 0; k < 10; ++k) v[k] = hr[k] * m;
    float mx = v[0];
    #pragma unroll
    for (int k = 1; k < 10; ++k) mx = fmaxf(mx, v[k]);
    float e[10];
    float s = 0.0f;
    #pragma unroll
    for (int k = 0; k < 10; ++k) { e[k] = expf(v[k] - mx); s += e[k]; }
    const float inv = 1.0f / s;
    #pragma unroll
    for (int k = 0; k < 10; ++k) out[(size_t)row * 10 + k] = e[k] * inv;
}

extern "C" void kernel_launch(void* const* d_in, const int* in_sizes, int n_in,
                              void* d_out, int out_size, void* d_ws, size_t ws_size,
                              hipStream_t stream)
{
    const float* x  = (const float*)d_in[0];
    const float* W1 = (const float*)d_in[1];
    const float* b1 = (const float*)d_in[2];
    const float* W2 = (const float*)d_in[3];
    const float* b2 = (const float*)d_in[4];
    const float* W3 = (const float*)d_in[5];
    const float* b3 = (const float*)d_in[6];
    const float* W4 = (const float*)d_in[7];
    const float* b4 = (const float*)d_in[8];

    float* out = (float*)d_out;                 // [65536,10]
    float* m1  = out + (size_t)BATCH * 10;      // [65536] each
    float* m2  = m1 + BATCH;
    float* m3  = m2 + BATCH;
    float* m4  = m3 + BATCH;

    float* ws    = (float*)d_ws;
    float* h1    = ws;                                  // 65536*512
    float* h2    = h1 + (size_t)BATCH * 512;            // 65536*256
    float* h3    = h2 + (size_t)BATCH * 256;            // 65536*10
    float* h4    = h3 + (size_t)BATCH * 10;             // 65536*10
    float* n1    = h4 + (size_t)BATCH * 10;             // 65536 x4
    float* n2    = n1 + BATCH;
    float* n3    = n2 + BATCH;
    float* n4    = n3 + BATCH;
    float* part  = n4 + BATCH;                          // 4*65536
    float* thr   = part + (size_t)4 * BATCH;            // 4

    // layer 1: x[65536,784] @ W1[784,512]  (BN=256 -> y=2; partials 0..3 as before)
    gemm_relu_norm<false><<<dim3(256, 2), 256, 0, stream>>>(x, W1, b1, nullptr, h1, part, 512, 784);
    reduce_norms_kernel<<<256, 256, 0, stream>>>(part, n1, 4);
    select_kernel<<<1, 1024, 0, stream>>>(n1, m1, thr + 0);

    // layer 2: (h1*m1)[65536,512] @ W2[512,256]  (y=1; partials 0..1 as before)
    gemm_relu_norm<true><<<dim3(256, 1), 256, 0, stream>>>(h1, W2, b2, m1, h2, part, 256, 512);
    reduce_norms_kernel<<<256, 256, 0, stream>>>(part, n2, 2);
    select_kernel<<<1, 1024, 0, stream>>>(n2, m2, thr + 1);

    // layer 3: (h2*m2)[65536,256] @ W3[256,10]
    layer3_kernel<<<1024, 256, 0, stream>>>(h2, W3, b3, m2, h3, n3);
    select_kernel<<<1, 1024, 0, stream>>>(n3, m3, thr + 2);

    // layer 4: (h3*m3)[65536,10] @ W4[10,10] (no relu)
    layer4_kernel<<<256, 256, 0, stream>>>(h3, W4, b4, m3, h4, n4);
    select_kernel<<<1, 1024, 0, stream>>>(n4, m4, thr + 3);

    // softmax(h4*m4)
    softmax_kernel<<<256, 256, 0, stream>>>(h4, m4, out);
}

// Round 5
// 1844.612 us; speedup vs baseline: 1.1095x; 1.1095x over previous
//
#include <hip/hip_runtime.h>
#include <cstdint>
#include <cstddef>

#define BATCH   65536
#define RANK_K  32769   // sorted_desc[32768] == 32769-th largest (1-indexed)

// ============ big GEMM (layers 1&2): C = relu((A*rowmask) @ B + bias), + per-row sum-of-squares partials ============
// v6: BM=256, BN=256, BK=16, 256 threads, 16x16 per thread, 1 block/CU.
//   16x16 rationale (v5): per-CU per kk LDS = 4 waves x 8 b128 x 12 = 384 cyc < FMA 512 cyc
//   -> FMA-issue-bound (16x8 was LDS-bound at ~80%).  v5's 2x regression was ALLOCATION,
//   not the tile: unroll-8 hoisted ~8 kk of fragments (256 live regs) on top of 256 acc
//   + 32 prefetch -> AGPR shuttle moves (VGPR 236, VALU 2.5x FMA).  v6 fixes:
//   (a) NO register prefetch (v2-style load->stage->bar->compute->bar);
//   (b) #pragma unroll 2 on kk -> <=64 live fragment regs; acc stays AGPR-resident
//       (round-0 evidence: FMA on AGPR acc runs full-rate at 84 arch VGPRs).
// BIT-EXACTNESS: identical per-element ascending-k single-register fmaf chain;
// bias->relu->square identical; norm partials reproduce the old 8-col grouping and
// partial slots exactly (validated in v5: absmax unchanged).  Masks cannot flip.
template<bool MASKED>
__global__ __launch_bounds__(256, 1)
void gemm_relu_norm(const float* __restrict__ A, const float* __restrict__ B,
                    const float* __restrict__ bias, const float* __restrict__ mask,
                    float* __restrict__ C, float* __restrict__ normPart,
                    const int N, const int K)
{
    __shared__ float As[16][260];   // [k][row], padded
    __shared__ float Bs[16][256];   // [k][col], granule-swizzled
    __shared__ float red[256][17];  // row-norm partial reduction (two passes)

    const int t    = threadIdx.x;
    const int tr   = t >> 4;          // 0..15 row group (16 rows each)
    const int tc   = t & 15;          // 0..15 col group (16 cols each)
    const int row0 = blockIdx.x * 256;
    const int col0 = blockIdx.y * 256;

    // A-load: thread t loads row (row0+t), 16 consecutive k per tile
    const float* Aptr = A + (size_t)(row0 + t) * K;
    // B-load: 16 k-rows x 256 cols; thread: k=t>>4, cols tc*16..+15
    const int bk = t >> 4;
    const float* Bptr = B + (size_t)bk * N + col0 + tc * 16;

    // swizzled Bs granule float-offsets: f(g) = g ^ ((g>>3)&7); same function on
    // store and read sides -> involution -> correct data; reads 2-way (free).
    const int g0 = ((tc << 2) + 0) ^ (tc >> 1);
    const int g1 = ((tc << 2) + 1) ^ (tc >> 1);
    const int g2 = ((tc << 2) + 2) ^ (tc >> 1);
    const int g3 = ((tc << 2) + 3) ^ (tc >> 1);
    const int bg0 = g0 << 2, bg1 = g1 << 2, bg2 = g2 << 2, bg3 = g3 << 2;

    float scale = 1.0f;
    if (MASKED) scale = mask[row0 + t];

    float acc[16][16];
    #pragma unroll
    for (int i = 0; i < 16; ++i)
        #pragma unroll
        for (int j = 0; j < 16; ++j) acc[i][j] = 0.0f;

    for (int k0 = 0; k0 < K; k0 += 16) {
        // ---- load current tile, stage to LDS (scale applied here, matches ref) ----
        float4 a0 = *(const float4*)(Aptr + k0);
        float4 a1 = *(const float4*)(Aptr + k0 + 4);
        float4 a2 = *(const float4*)(Aptr + k0 + 8);
        float4 a3 = *(const float4*)(Aptr + k0 + 12);
        float4 b0 = *(const float4*)(Bptr + (size_t)k0 * N);
        float4 b1 = *(const float4*)(Bptr + (size_t)k0 * N + 4);
        float4 b2 = *(const float4*)(Bptr + (size_t)k0 * N + 8);
        float4 b3 = *(const float4*)(Bptr + (size_t)k0 * N + 12);
        if (MASKED) {
            a0.x *= scale; a0.y *= scale; a0.z *= scale; a0.w *= scale;
            a1.x *= scale; a1.y *= scale; a1.z *= scale; a1.w *= scale;
            a2.x *= scale; a2.y *= scale; a2.z *= scale; a2.w *= scale;
            a3.x *= scale; a3.y *= scale; a3.z *= scale; a3.w *= scale;
        }
        As[ 0][t] = a0.x; As[ 1][t] = a0.y; As[ 2][t] = a0.z; As[ 3][t] = a0.w;
        As[ 4][t] = a1.x; As[ 5][t] = a1.y; As[ 6][t] = a1.z; As[ 7][t] = a1.w;
        As[ 8][t] = a2.x; As[ 9][t] = a2.y; As[10][t] = a2.z; As[11][t] = a2.w;
        As[12][t] = a3.x; As[13][t] = a3.y; As[14][t] = a3.z; As[15][t] = a3.w;
        *(float4*)&Bs[bk][bg0] = b0;   // swizzled granule stores
        *(float4*)&Bs[bk][bg1] = b1;
        *(float4*)&Bs[bk][bg2] = b2;
        *(float4*)&Bs[bk][bg3] = b3;
        __syncthreads();

        // ---- compute current tile from LDS; unroll 2 caps live fragments at 64 regs ----
        #pragma unroll 2
        for (int kk = 0; kk < 16; ++kk) {
            float a_[16], b_[16];
            *(float4*)&a_[0]  = *(const float4*)&As[kk][tr*16];
            *(float4*)&a_[4]  = *(const float4*)&As[kk][tr*16 + 4];
            *(float4*)&a_[8]  = *(const float4*)&As[kk][tr*16 + 8];
            *(float4*)&a_[12] = *(const float4*)&As[kk][tr*16 + 12];
            *(float4*)&b_[0]  = *(const float4*)&Bs[kk][bg0];
            *(float4*)&b_[4]  = *(const float4*)&Bs[kk][bg1];
            *(float4*)&b_[8]  = *(const float4*)&Bs[kk][bg2];
            *(float4*)&b_[12] = *(const float4*)&Bs[kk][bg3];
            #pragma unroll
            for (int i = 0; i < 16; ++i)
                #pragma unroll
                for (int j = 0; j < 16; ++j)
                    acc[i][j] = fmaf(a_[i], b_[j], acc[i][j]);
        }
        __syncthreads();
    }

    float bv[16];
    #pragma unroll
    for (int j = 0; j < 16; ++j) bv[j] = bias[col0 + tc*16 + j];

    // bias -> relu in place (same per-element op and order as validated kernel)
    #pragma unroll
    for (int i = 0; i < 16; ++i)
        #pragma unroll
        for (int j = 0; j < 16; ++j)
            acc[i][j] = fmaxf(acc[i][j] + bv[j], 0.0f);

    #pragma unroll
    for (int i = 0; i < 16; ++i) {
        const size_t row = (size_t)(row0 + tr*16 + i);
        *(float4*)&C[row * N + col0 + tc*16]      = *(float4*)&acc[i][0];
        *(float4*)&C[row * N + col0 + tc*16 + 4]  = *(float4*)&acc[i][4];
        *(float4*)&C[row * N + col0 + tc*16 + 8]  = *(float4*)&acc[i][8];
        *(float4*)&C[row * N + col0 + tc*16 + 12] = *(float4*)&acc[i][12];
    }

    // per-row group sums: cols j=0..7 = old group 2tc, j=8..15 = old group 2tc+1
    // (fresh fmaf chains, j ascending — identical to old per-group chains)
    float slo[16], shi[16];
    #pragma unroll
    for (int i = 0; i < 16; ++i) {
        float s = 0.0f;
        #pragma unroll
        for (int j = 0; j < 8; ++j) s = fmaf(acc[i][j], acc[i][j], s);
        slo[i] = s;
        s = 0.0f;
        #pragma unroll
        for (int j = 8; j < 16; ++j) s = fmaf(acc[i][j], acc[i][j], s);
        shi[i] = s;
    }

    // pass 1: old y-partial p = 2*blockIdx.y (cols [col0, col0+128) -> threads tc<8)
    if (tc < 8) {
        #pragma unroll
        for (int i = 0; i < 16; ++i) {
            red[tr*16 + i][2*tc]     = slo[i];
            red[tr*16 + i][2*tc + 1] = shi[i];
        }
    }
    __syncthreads();
    {
        float s = 0.0f;
        #pragma unroll
        for (int x = 0; x < 16; ++x) s += red[t][x];    // fixed ascending order
        normPart[(size_t)(2*blockIdx.y) * BATCH + row0 + t] = s;
    }
    __syncthreads();
    // pass 2: old y-partial p = 2*blockIdx.y + 1 (cols [col0+128, col0+256))
    if (tc >= 8) {
        #pragma unroll
        for (int i = 0; i < 16; ++i) {
            red[tr*16 + i][2*(tc-8)]     = slo[i];
            red[tr*16 + i][2*(tc-8) + 1] = shi[i];
        }
    }
    __syncthreads();
    {
        float s = 0.0f;
        #pragma unroll
        for (int x = 0; x < 16; ++x) s += red[t][x];    // fixed ascending order
        normPart[(size_t)(2*blockIdx.y + 1) * BATCH + row0 + t] = s;
    }
}

// ============ fused: partial-sum -> norm -> exact 32769-th-largest -> mask ============
// NPART>=1: src = part[NPART][BATCH]; norm = sqrt((double)sum_p part[p][i]), p ascending
//           (chain identical to the old reduce_norms_kernel -> bit-identical norms).
// NPART==0: src = norms (already sqrt'd by layer3/layer4 kernels), used directly.
template<int NPART>
__global__ __launch_bounds__(1024)
void select_kernel(const float* __restrict__ src, float* __restrict__ maskOut,
                   float* __restrict__ thrOut)
{
    __shared__ int wsum[16];

    const int t = threadIdx.x;
    unsigned key[64];
    #pragma unroll
    for (int i = 0; i < 16; ++i) {
        float4 v;
        if (NPART == 0) {
            v = ((const float4*)src)[i * 1024 + t];
        } else {
            float4 s = ((const float4*)src)[i * 1024 + t];
            #pragma unroll
            for (int p = 1; p < NPART; ++p) {
                float4 w = ((const float4*)(src + (size_t)p * BATCH))[i * 1024 + t];
                s.x += w.x; s.y += w.y; s.z += w.z; s.w += w.w;   // p ascending, matches old
            }
            v.x = (float)sqrt((double)s.x);
            v.y = (float)sqrt((double)s.y);
            v.z = (float)sqrt((double)s.z);
            v.w = (float)sqrt((double)s.w);
        }
        key[i*4+0] = __float_as_uint(v.x);
        key[i*4+1] = __float_as_uint(v.y);
        key[i*4+2] = __float_as_uint(v.z);
        key[i*4+3] = __float_as_uint(v.w);      // nonneg floats -> monotone uint order
    }

    // V = min{ T : count(key > T) < RANK_K }  == exact RANK_K-th largest value
    unsigned lo = 0u, hi = 0x7F800000u;
    while (lo < hi) {                            // uniform across all threads
        const unsigned mid = lo + ((hi - lo) >> 1);
        int c = 0;
        #pragma unroll
        for (int i = 0; i < 64; ++i) c += (key[i] > mid) ? 1 : 0;
        #pragma unroll
        for (int off = 32; off > 0; off >>= 1) c += __shfl_down(c, off, 64);
        if ((t & 63) == 0) wsum[t >> 6] = c;
        __syncthreads();
        int total = 0;
        #pragma unroll
        for (int w = 0; w < 16; ++w) total += wsum[w];
        if (total < RANK_K) hi = mid; else lo = mid + 1;
        __syncthreads();
    }

    if (t == 0) thrOut[0] = __uint_as_float(lo);
    float4* m4 = (float4*)maskOut;
    #pragma unroll
    for (int i = 0; i < 16; ++i) {
        float4 m;
        m.x = (key[i*4+0] > lo) ? 1.0f : 0.0f;
        m.y = (key[i*4+1] > lo) ? 1.0f : 0.0f;
        m.z = (key[i*4+2] > lo) ? 1.0f : 0.0f;
        m.w = (key[i*4+3] > lo) ? 1.0f : 0.0f;   // strict > like reference
        m4[i * 1024 + t] = m;
    }
}

// ============ layer 3: h3 = relu((h2*m2) @ W3[256x10] + b3), full row norms ============
__global__ __launch_bounds__(256)
void layer3_kernel(const float* __restrict__ h2, const float* __restrict__ W3,
                   const float* __restrict__ b3, const float* __restrict__ mask2,
                   float* __restrict__ h3, float* __restrict__ norms3)
{
    __shared__ float wT[10][260];   // transposed W3 for b128 broadcast reads
    __shared__ float red[64][5];

    const int t    = threadIdx.x;
    const int r    = t & 63;
    const int g    = t >> 6;          // 0..3 column groups (3,3,3,1)
    const int j0   = g * 3;
    const int nj   = (g == 3) ? 1 : 3;
    const int row0 = blockIdx.x * 64;
    const int row  = row0 + r;

    for (int e = t; e < 2560; e += 256) wT[e % 10][e / 10] = W3[e];
    __syncthreads();

    const float m = mask2[row];
    const float* hrow = h2 + (size_t)row * 256;

    float acc[3] = {0.0f, 0.0f, 0.0f};
    for (int k = 0; k < 256; k += 4) {
        float4 v = *(const float4*)(hrow + k);
        v.x *= m; v.y *= m; v.z *= m; v.w *= m;
        float4 w0 = *(const float4*)&wT[j0][k];
        acc[0] += v.x*w0.x + v.y*w0.y + v.z*w0.z + v.w*w0.w;
        if (nj > 1) {
            float4 w1 = *(const float4*)&wT[j0+1][k];
            acc[1] += v.x*w1.x + v.y*w1.y + v.z*w1.z + v.w*w1.w;
            float4 w2 = *(const float4*)&wT[j0+2][k];
            acc[2] += v.x*w2.x + v.y*w2.y + v.z*w2.z + v.w*w2.w;
        }
    }

    float ss = 0.0f;
    for (int jj = 0; jj < nj; ++jj) {
        float v = fmaxf(acc[jj] + b3[j0 + jj], 0.0f);
        h3[(size_t)row * 10 + j0 + jj] = v;
        ss += v * v;
    }
    red[r][g] = ss;
    __syncthreads();
    if (t < 64) {
        float s = red[t][0] + red[t][1] + red[t][2] + red[t][3];  // fixed order
        norms3[row0 + t] = (float)sqrt((double)s);
    }
}

// ============ layer 4: h4 = (h3*m3) @ W4[10x10] + b4 (no relu), norms ============
__global__ __launch_bounds__(256)
void layer4_kernel(const float* __restrict__ h3, const float* __restrict__ W4,
                   const float* __restrict__ b4, const float* __restrict__ mask3,
                   float* __restrict__ h4, float* __restrict__ norms4)
{
    __shared__ float w[100];
    __shared__ float bb[10];
    const int t = threadIdx.x;
    if (t < 100) w[t] = W4[t];
    if (t < 10)  bb[t] = b4[t];
    __syncthreads();

    const int row = blockIdx.x * 256 + t;
    const float m = mask3[row];
    const float* hr = h3 + (size_t)row * 10;
    float v[10];
    #pragma unroll
    for (int k = 0; k < 10; ++k) v[k] = hr[k] * m;

    float s = 0.0f;
    #pragma unroll
    for (int j = 0; j < 10; ++j) {
        float a = 0.0f;
        #pragma unroll
        for (int k = 0; k < 10; ++k) a = fmaf(v[k], w[k*10 + j], a);
        a += bb[j];                     // dot then +bias (matches ref)
        h4[(size_t)row * 10 + j] = a;
        s = fmaf(a, a, s);
    }
    norms4[row] = (float)sqrt((double)s);
}

// ============ final: out = softmax(h4 * m4) ============
__global__ __launch_bounds__(256)
void softmax_kernel(const float* __restrict__ h4, const float* __restrict__ mask4,
                    float* __restrict__ out)
{
    const int t   = threadIdx.x;
    const int row = blockIdx.x * 256 + t;
    const float m = mask4[row];
    const float* hr = h4 + (size_t)row * 10;
    float v[10];
    #pragma unroll
    for (int k = 0; k < 10; ++k) v[k] = hr[k] * m;
    float mx = v[0];
    #pragma unroll
    for (int k = 1; k < 10; ++k) mx = fmaxf(mx, v[k]);
    float e[10];
    float s = 0.0f;
    #pragma unroll
    for (int k = 0; k < 10; ++k) { e[k] = expf(v[k] - mx); s += e[k]; }
    const float inv = 1.0f / s;
    #pragma unroll
    for (int k = 0; k < 10; ++k) out[(size_t)row * 10 + k] = e[k] * inv;
}

extern "C" void kernel_launch(void* const* d_in, const int* in_sizes, int n_in,
                              void* d_out, int out_size, void* d_ws, size_t ws_size,
                              hipStream_t stream)
{
    const float* x  = (const float*)d_in[0];
    const float* W1 = (const float*)d_in[1];
    const float* b1 = (const float*)d_in[2];
    const float* W2 = (const float*)d_in[3];
    const float* b2 = (const float*)d_in[4];
    const float* W3 = (const float*)d_in[5];
    const float* b3 = (const float*)d_in[6];
    const float* W4 = (const float*)d_in[7];
    const float* b4 = (const float*)d_in[8];

    float* out = (float*)d_out;                 // [65536,10]
    float* m1  = out + (size_t)BATCH * 10;      // [65536] each
    float* m2  = m1 + BATCH;
    float* m3  = m2 + BATCH;
    float* m4  = m3 + BATCH;

    float* ws    = (float*)d_ws;
    float* h1    = ws;                                  // 65536*512
    float* h2    = h1 + (size_t)BATCH * 512;            // 65536*256
    float* h3    = h2 + (size_t)BATCH * 256;            // 65536*10
    float* h4    = h3 + (size_t)BATCH * 10;             // 65536*10
    float* n1    = h4 + (size_t)BATCH * 10;             // 65536 x4 (n1/n2 now unused)
    float* n2    = n1 + BATCH;
    float* n3    = n2 + BATCH;
    float* n4    = n3 + BATCH;
    float* part  = n4 + BATCH;                          // 4*65536
    float* thr   = part + (size_t)4 * BATCH;            // 4

    // layer 1: x[65536,784] @ W1[784,512]  (BN=256 -> y=2; partials 0..3 as before)
    gemm_relu_norm<false><<<dim3(256, 2), 256, 0, stream>>>(x, W1, b1, nullptr, h1, part, 512, 784);
    select_kernel<4><<<1, 1024, 0, stream>>>(part, m1, thr + 0);

    // layer 2: (h1*m1)[65536,512] @ W2[512,256]  (y=1; partials 0..1 as before)
    gemm_relu_norm<true><<<dim3(256, 1), 256, 0, stream>>>(h1, W2, b2, m1, h2, part, 256, 512);
    select_kernel<2><<<1, 1024, 0, stream>>>(part, m2, thr + 1);

    // layer 3: (h2*m2)[65536,256] @ W3[256,10]
    layer3_kernel<<<1024, 256, 0, stream>>>(h2, W3, b3, m2, h3, n3);
    select_kernel<0><<<1, 1024, 0, stream>>>(n3, m3, thr + 2);

    // layer 4: (h3*m3)[65536,10] @ W4[10,10] (no relu)
    layer4_kernel<<<256, 256, 0, stream>>>(h3, W4, b4, m3, h4, n4);
    select_kernel<0><<<1, 1024, 0, stream>>>(n4, m4, thr + 3);

    // softmax(h4*m4)
    softmax_kernel<<<256, 256, 0, stream>>>(h4, m4, out);
}

// Round 6
// 1308.422 us; speedup vs baseline: 1.5642x; 1.4098x over previous
//
#include <hip/hip_runtime.h>
#include <cstdint>
#include <cstddef>

#define BATCH   65536
#define RANK_K  32769   // sorted_desc[32768] == 32769-th largest (1-indexed)

// direct global->LDS async copy, 16B per lane (dest = wave-uniform base + lane*16; source per-lane)
__device__ __forceinline__ void glds16(const float* gsrc, float* ldst)
{
    __builtin_amdgcn_global_load_lds(
        (const __attribute__((address_space(1))) void*)gsrc,
        (__attribute__((address_space(3))) void*)ldst,
        16, 0, 0);
}

// ============ big GEMM (layers 1&2): C = relu((A*rowmask) @ B + bias), + per-row sum-of-squares partials ============
// v7: BM=256, BN=128, BK=16, 256 threads, 16x8/thread (v3's allocator-proven geometry, acc=128 in AGPR),
//     but staging via global_load_lds into DOUBLE-BUFFERED LDS, ONE barrier per tile:
//       sync; issue 6 glds for tile t+1 into buf^1; compute tile t from buf; (next sync drains)
//     -> load latency + staging hidden under compute, zero data through VGPRs (round-1's failure
//        was A-REGISTER-prefetch liveness, not glds).
//   A needs no transpose: glds sources are per-lane, so LDS layout As[q][row][4] (k-quad granules);
//     lane deposits A[row][k0+4q..+3] (contiguous 16B in global).  Row-swizzle sigma(l)=l^((l>>4)&3)
//     (involution) on the SOURCE row so reads at tr*16+(i^(tr&3)) hit 4 distinct bank-quads.
//   B: round-1-VALIDATED source-granule swizzle swz(g)=g^((g>>4)&1) + v3's read-side XOR (bo_lo/bo_hi).
//   Layer-2 row mask moved to EPILOGUE: mask in {0.0f,1.0f} exactly -> relu(m*acc+b) bit-identical
//     to relu(sum((m*a)*b)+b)  (x1.0 exact identity; x0.0 -> +-0, +-0+b == b exactly).
// BIT-EXACTNESS: per-output-element fmaf chain is single-register, k ascending (q-major, kk 0..3);
// bias->relu->square->16-group row reduction identical to validated kernel -> masks cannot flip.
template<bool MASKED>
__global__ __launch_bounds__(256, 2)
void gemm_relu_norm(const float* __restrict__ A, const float* __restrict__ B,
                    const float* __restrict__ bias, const float* __restrict__ mask,
                    float* __restrict__ C, float* __restrict__ normPart,
                    const int N, const int K)
{
    __shared__ float As[2][4][256][4];   // [buf][kquad][row-granule][k-in-quad]  (32 KB)
    __shared__ float Bs[2][16][128];     // [buf][krow][col], granule-swizzled    (16 KB)

    const int t    = threadIdx.x;
    const int tr   = t >> 4;          // 0..15 row group (16 rows each)
    const int tc   = t & 15;          // 0..15 col group (8 cols each)
    const int am   = tr & 3;          // A-read row-swizzle key
    const int w    = t >> 6;          // wave id 0..3
    const int row0 = blockIdx.x * 256;
    const int col0 = blockIdx.y * 128;

    // glds A source: lane l deposits logical row w*64 + sigma(l), granule l
    const int asrow = (t & ~63) + ((t & 63) ^ ((t >> 4) & 3));
    const float* Asrc = A + (size_t)(row0 + asrow) * K;          // + k0 + g*4 per call
    // glds B source: instr h covers k-rows {w*4+2h, w*4+2h+1}; lane l -> row +(l>>5),
    // col granule swz(l&31) (so LDS granule g holds source granule swz(g))
    const int brow = w * 4 + ((t >> 5) & 1);
    const int bcol = col0 + (((t & 31) ^ ((t >> 4) & 1)) << 2);
    const float* Bsrc = B + (size_t)brow * N + bcol;             // + (k0 + 2h)*N per call

    // B read offsets (involution with store side -- validated round 1/2)
    const int bsw   = ((tc >> 3) & 1) << 2;
    const int bo_lo = (tc * 8) ^ bsw;
    const int bo_hi = (tc * 8 + 4) ^ bsw;

    float acc[16][8];
    #pragma unroll
    for (int i = 0; i < 16; ++i)
        #pragma unroll
        for (int j = 0; j < 8; ++j) acc[i][j] = 0.0f;

    const int nT = K >> 4;

    // ---- prologue: stage tile 0 into buf 0 ----
    #pragma unroll
    for (int g = 0; g < 4; ++g)
        glds16(Asrc + g * 4, &As[0][g][w * 64][0]);
    glds16(Bsrc,               &Bs[0][w * 4][0]);
    glds16(Bsrc + 2 * (size_t)N, &Bs[0][w * 4 + 2][0]);

    for (int tile = 0; tile < nT; ++tile) {
        const int cur = tile & 1;
        __syncthreads();   // drains this wave's glds (vmcnt0) + prior ds ops; 'cur' ready

        if (tile + 1 < nT) {             // issue next-tile staging into the other buffer
            const int nxt = cur ^ 1;
            const int k0n = (tile + 1) << 4;
            #pragma unroll
            for (int g = 0; g < 4; ++g)
                glds16(Asrc + k0n + g * 4, &As[nxt][g][w * 64][0]);
            glds16(Bsrc + (size_t)k0n * N,       &Bs[nxt][w * 4][0]);
            glds16(Bsrc + (size_t)(k0n + 2) * N, &Bs[nxt][w * 4 + 2][0]);
        }

        // ---- compute current tile; unroll 1 on q caps live fragments at ~36 floats ----
        #pragma unroll 1
        for (int q = 0; q < 4; ++q) {
            float b_[4][8];
            #pragma unroll
            for (int kk = 0; kk < 4; ++kk) {
                *(float4*)&b_[kk][0] = *(const float4*)&Bs[cur][q * 4 + kk][bo_lo];
                *(float4*)&b_[kk][4] = *(const float4*)&Bs[cur][q * 4 + kk][bo_hi];
            }
            #pragma unroll
            for (int i = 0; i < 16; ++i) {
                float a4[4];
                *(float4*)&a4[0] = *(const float4*)&As[cur][q][tr * 16 + (i ^ am)][0];
                #pragma unroll
                for (int kk = 0; kk < 4; ++kk)   // k = q*4+kk ascending per acc element
                    #pragma unroll
                    for (int j = 0; j < 8; ++j)
                        acc[i][j] = fmaf(a4[kk], b_[kk][j], acc[i][j]);
            }
        }
    }

    float bv[8];
    #pragma unroll
    for (int j = 0; j < 8; ++j) bv[j] = bias[col0 + tc * 8 + j];

    float mrow[16];
    if (MASKED) {
        #pragma unroll
        for (int c = 0; c < 4; ++c)
            *(float4*)&mrow[c * 4] = *(const float4*)&mask[row0 + tr * 16 + c * 4];
    }

    float rowsum[16];
    #pragma unroll
    for (int i = 0; i < 16; ++i) {
        float s = 0.0f;
        #pragma unroll
        for (int j = 0; j < 8; ++j) {
            float pv = MASKED ? acc[i][j] * mrow[i] : acc[i][j];  // exact: m in {0,1}
            float v  = fmaxf(pv + bv[j], 0.0f);                   // +bias, relu (matches ref)
            acc[i][j] = v;
            s = fmaf(v, v, s);
        }
        rowsum[i] = s;
    }

    #pragma unroll
    for (int i = 0; i < 16; ++i) {
        const size_t row = (size_t)(row0 + tr * 16 + i);
        *(float4*)&C[row * N + col0 + tc * 8]     = *(float4*)&acc[i][0];
        *(float4*)&C[row * N + col0 + tc * 8 + 4] = *(float4*)&acc[i][4];
    }

    // red aliases the (now dead) A buffers: 256*17*4 = 17408 B <= 32768 B
    __syncthreads();                       // all waves done reading As/Bs
    float (*red)[17] = (float (*)[17])(&As[0][0][0][0]);
    #pragma unroll
    for (int i = 0; i < 16; ++i) red[tr * 16 + i][tc] = rowsum[i];
    __syncthreads();
    {
        float s = 0.0f;
        #pragma unroll
        for (int x = 0; x < 16; ++x) s += red[t][x];    // fixed order -> deterministic
        normPart[(size_t)blockIdx.y * BATCH + row0 + t] = s;
    }
}

// ============ fused: partial-sum -> norm -> exact 32769-th-largest -> mask ============
// NPART>=1: src = part[NPART][BATCH]; norm = sqrt((double)sum_p part[p][i]), p ascending
//           (chain identical to the old reduce_norms_kernel -> bit-identical norms).
// NPART==0: src = norms (already sqrt'd by layer3/layer4 kernels), used directly.
template<int NPART>
__global__ __launch_bounds__(1024)
void select_kernel(const float* __restrict__ src, float* __restrict__ maskOut,
                   float* __restrict__ thrOut)
{
    __shared__ int wsum[16];

    const int t = threadIdx.x;
    unsigned key[64];
    #pragma unroll
    for (int i = 0; i < 16; ++i) {
        float4 v;
        if (NPART == 0) {
            v = ((const float4*)src)[i * 1024 + t];
        } else {
            float4 s = ((const float4*)src)[i * 1024 + t];
            #pragma unroll
            for (int p = 1; p < NPART; ++p) {
                float4 w = ((const float4*)(src + (size_t)p * BATCH))[i * 1024 + t];
                s.x += w.x; s.y += w.y; s.z += w.z; s.w += w.w;   // p ascending, matches old
            }
            v.x = (float)sqrt((double)s.x);
            v.y = (float)sqrt((double)s.y);
            v.z = (float)sqrt((double)s.z);
            v.w = (float)sqrt((double)s.w);
        }
        key[i*4+0] = __float_as_uint(v.x);
        key[i*4+1] = __float_as_uint(v.y);
        key[i*4+2] = __float_as_uint(v.z);
        key[i*4+3] = __float_as_uint(v.w);      // nonneg floats -> monotone uint order
    }

    // V = min{ T : count(key > T) < RANK_K }  == exact RANK_K-th largest value
    unsigned lo = 0u, hi = 0x7F800000u;
    while (lo < hi) {                            // uniform across all threads
        const unsigned mid = lo + ((hi - lo) >> 1);
        int c = 0;
        #pragma unroll
        for (int i = 0; i < 64; ++i) c += (key[i] > mid) ? 1 : 0;
        #pragma unroll
        for (int off = 32; off > 0; off >>= 1) c += __shfl_down(c, off, 64);
        if ((t & 63) == 0) wsum[t >> 6] = c;
        __syncthreads();
        int total = 0;
        #pragma unroll
        for (int w = 0; w < 16; ++w) total += wsum[w];
        if (total < RANK_K) hi = mid; else lo = mid + 1;
        __syncthreads();
    }

    if (t == 0) thrOut[0] = __uint_as_float(lo);
    float4* m4 = (float4*)maskOut;
    #pragma unroll
    for (int i = 0; i < 16; ++i) {
        float4 m;
        m.x = (key[i*4+0] > lo) ? 1.0f : 0.0f;
        m.y = (key[i*4+1] > lo) ? 1.0f : 0.0f;
        m.z = (key[i*4+2] > lo) ? 1.0f : 0.0f;
        m.w = (key[i*4+3] > lo) ? 1.0f : 0.0f;   // strict > like reference
        m4[i * 1024 + t] = m;
    }
}

// ============ layer 3: h3 = relu((h2*m2) @ W3[256x10] + b3), full row norms ============
__global__ __launch_bounds__(256)
void layer3_kernel(const float* __restrict__ h2, const float* __restrict__ W3,
                   const float* __restrict__ b3, const float* __restrict__ mask2,
                   float* __restrict__ h3, float* __restrict__ norms3)
{
    __shared__ float wT[10][260];   // transposed W3 for b128 broadcast reads
    __shared__ float red[64][5];

    const int t    = threadIdx.x;
    const int r    = t & 63;
    const int g    = t >> 6;          // 0..3 column groups (3,3,3,1)
    const int j0   = g * 3;
    const int nj   = (g == 3) ? 1 : 3;
    const int row0 = blockIdx.x * 64;
    const int row  = row0 + r;

    for (int e = t; e < 2560; e += 256) wT[e % 10][e / 10] = W3[e];
    __syncthreads();

    const float m = mask2[row];
    const float* hrow = h2 + (size_t)row * 256;

    float acc[3] = {0.0f, 0.0f, 0.0f};
    for (int k = 0; k < 256; k += 4) {
        float4 v = *(const float4*)(hrow + k);
        v.x *= m; v.y *= m; v.z *= m; v.w *= m;
        float4 w0 = *(const float4*)&wT[j0][k];
        acc[0] += v.x*w0.x + v.y*w0.y + v.z*w0.z + v.w*w0.w;
        if (nj > 1) {
            float4 w1 = *(const float4*)&wT[j0+1][k];
            acc[1] += v.x*w1.x + v.y*w1.y + v.z*w1.z + v.w*w1.w;
            float4 w2 = *(const float4*)&wT[j0+2][k];
            acc[2] += v.x*w2.x + v.y*w2.y + v.z*w2.z + v.w*w2.w;
        }
    }

    float ss = 0.0f;
    for (int jj = 0; jj < nj; ++jj) {
        float v = fmaxf(acc[jj] + b3[j0 + jj], 0.0f);
        h3[(size_t)row * 10 + j0 + jj] = v;
        ss += v * v;
    }
    red[r][g] = ss;
    __syncthreads();
    if (t < 64) {
        float s = red[t][0] + red[t][1] + red[t][2] + red[t][3];  // fixed order
        norms3[row0 + t] = (float)sqrt((double)s);
    }
}

// ============ layer 4: h4 = (h3*m3) @ W4[10x10] + b4 (no relu), norms ============
__global__ __launch_bounds__(256)
void layer4_kernel(const float* __restrict__ h3, const float* __restrict__ W4,
                   const float* __restrict__ b4, const float* __restrict__ mask3,
                   float* __restrict__ h4, float* __restrict__ norms4)
{
    __shared__ float w[100];
    __shared__ float bb[10];
    const int t = threadIdx.x;
    if (t < 100) w[t] = W4[t];
    if (t < 10)  bb[t] = b4[t];
    __syncthreads();

    const int row = blockIdx.x * 256 + t;
    const float m = mask3[row];
    const float* hr = h3 + (size_t)row * 10;
    float v[10];
    #pragma unroll
    for (int k = 0; k < 10; ++k) v[k] = hr[k] * m;

    float s = 0.0f;
    #pragma unroll
    for (int j = 0; j < 10; ++j) {
        float a = 0.0f;
        #pragma unroll
        for (int k = 0; k < 10; ++k) a = fmaf(v[k], w[k*10 + j], a);
        a += bb[j];                     // dot then +bias (matches ref)
        h4[(size_t)row * 10 + j] = a;
        s = fmaf(a, a, s);
    }
    norms4[row] = (float)sqrt((double)s);
}

// ============ final: out = softmax(h4 * m4) ============
__global__ __launch_bounds__(256)
void softmax_kernel(const float* __restrict__ h4, const float* __restrict__ mask4,
                    float* __restrict__ out)
{
    const int t   = threadIdx.x;
    const int row = blockIdx.x * 256 + t;
    const float m = mask4[row];
    const float* hr = h4 + (size_t)row * 10;
    float v[10];
    #pragma unroll
    for (int k = 0; k < 10; ++k) v[k] = hr[k] * m;
    float mx = v[0];
    #pragma unroll
    for (int k = 1; k < 10; ++k) mx = fmaxf(mx, v[k]);
    float e[10];
    float s = 0.0f;
    #pragma unroll
    for (int k = 0; k < 10; ++k) { e[k] = expf(v[k] - mx); s += e[k]; }
    const float inv = 1.0f / s;
    #pragma unroll
    for (int k = 0; k < 10; ++k) out[(size_t)row * 10 + k] = e[k] * inv;
}

extern "C" void kernel_launch(void* const* d_in, const int* in_sizes, int n_in,
                              void* d_out, int out_size, void* d_ws, size_t ws_size,
                              hipStream_t stream)
{
    const float* x  = (const float*)d_in[0];
    const float* W1 = (const float*)d_in[1];
    const float* b1 = (const float*)d_in[2];
    const float* W2 = (const float*)d_in[3];
    const float* b2 = (const float*)d_in[4];
    const float* W3 = (const float*)d_in[5];
    const float* b3 = (const float*)d_in[6];
    const float* W4 = (const float*)d_in[7];
    const float* b4 = (const float*)d_in[8];

    float* out = (float*)d_out;                 // [65536,10]
    float* m1  = out + (size_t)BATCH * 10;      // [65536] each
    float* m2  = m1 + BATCH;
    float* m3  = m2 + BATCH;
    float* m4  = m3 + BATCH;

    float* ws    = (float*)d_ws;
    float* h1    = ws;                                  // 65536*512
    float* h2    = h1 + (size_t)BATCH * 512;            // 65536*256
    float* h3    = h2 + (size_t)BATCH * 256;            // 65536*10
    float* h4    = h3 + (size_t)BATCH * 10;             // 65536*10
    float* n1    = h4 + (size_t)BATCH * 10;             // 65536 x4 (n1/n2 unused)
    float* n2    = n1 + BATCH;
    float* n3    = n2 + BATCH;
    float* n4    = n3 + BATCH;
    float* part  = n4 + BATCH;                          // 4*65536
    float* thr   = part + (size_t)4 * BATCH;            // 4

    // layer 1: x[65536,784] @ W1[784,512]  (BN=128 -> 4 y-blocks -> partials 0..3 as validated)
    gemm_relu_norm<false><<<dim3(256, 4), 256, 0, stream>>>(x, W1, b1, nullptr, h1, part, 512, 784);
    select_kernel<4><<<1, 1024, 0, stream>>>(part, m1, thr + 0);

    // layer 2: (h1*m1)[65536,512] @ W2[512,256]  (mask applied in epilogue, exact)
    gemm_relu_norm<true><<<dim3(256, 2), 256, 0, stream>>>(h1, W2, b2, m1, h2, part, 256, 512);
    select_kernel<2><<<1, 1024, 0, stream>>>(part, m2, thr + 1);

    // layer 3: (h2*m2)[65536,256] @ W3[256,10]
    layer3_kernel<<<1024, 256, 0, stream>>>(h2, W3, b3, m2, h3, n3);
    select_kernel<0><<<1, 1024, 0, stream>>>(n3, m3, thr + 2);

    // layer 4: (h3*m3)[65536,10] @ W4[10,10] (no relu)
    layer4_kernel<<<256, 256, 0, stream>>>(h3, W4, b4, m3, h4, n4);
    select_kernel<0><<<1, 1024, 0, stream>>>(n4, m4, thr + 3);

    // softmax(h4*m4)
    softmax_kernel<<<256, 256, 0, stream>>>(h4, m4, out);
}